// Round 4
// baseline (376.024 us; speedup 1.0000x reference)
//
#include <hip/hip_runtime.h>
#include <stdint.h>

typedef unsigned short ushort_t;
typedef __attribute__((ext_vector_type(8))) short short8;
typedef __attribute__((ext_vector_type(4))) float floatx4;

#define B_   8192
#define IN_  1024
#define H_   1024

#define XB_ELEMS   (B_ * IN_)            // 8388608
#define WB_ELEMS   (H_ * IN_)            // 1048576
// ws layout (ushort elements): Xb[8M] | Hb[8M] | Wb[8][1M]  (slots: i,f,g,o x-weights then i,f,g,o h-weights)
#define WS_XB   0
#define WS_HB   XB_ELEMS
#define WS_WB   (2 * XB_ELEMS)

__device__ __forceinline__ ushort_t f2bf(float f) {
    union { float f; uint32_t i; } v; v.f = f;
    uint32_t r = (v.i + 0x7fffu + ((v.i >> 16) & 1u)) >> 16;
    return (ushort_t)r;
}
__device__ __forceinline__ float sigmoid_(float x) {
    return 1.0f / (1.0f + __expf(-x));
}
__device__ __forceinline__ float tanh_(float x) {
    float xc = fminf(fmaxf(x, -20.f), 20.f);
    float e = __expf(2.f * xc);
    return (e - 1.f) / (e + 1.f);
}

// ---- prep: f32 -> bf16 for x, h, 8 weight matrices into ws ----
// 8 elements per thread. chunks: x 2^20, h 2^20, each W 2^17 -> total 3145728.
__global__ __launch_bounds__(256) void cvt_kernel(
    const float* __restrict__ X,   const float* __restrict__ Hin,
    const float* __restrict__ Wix, const float* __restrict__ Wfx,
    const float* __restrict__ Wgx, const float* __restrict__ Wox,
    const float* __restrict__ Wih, const float* __restrict__ Wfh,
    const float* __restrict__ Wgh, const float* __restrict__ Woh,
    ushort_t* __restrict__ ws)
{
    const int c = blockIdx.x * 256 + threadIdx.x;
    const float* src;
    ushort_t* dst;
    int off;
    if (c < 2097152) {
        const int t = c >> 20;                 // 0 = x, 1 = h
        src = t ? Hin : X;
        dst = ws + (t ? WS_HB : WS_XB);
        off = (c & 1048575) * 8;
    } else {
        const int cc = c - 2097152;
        const int s = cc >> 17;                // weight slot 0..7
        const float* w =
            s == 0 ? Wix : s == 1 ? Wfx : s == 2 ? Wgx : s == 3 ? Wox :
            s == 4 ? Wih : s == 5 ? Wfh : s == 6 ? Wgh : Woh;
        src = w;
        dst = ws + WS_WB + s * WB_ELEMS;
        off = (cc & 131071) * 8;
    }
    float4 f0 = *(const float4*)(src + off);
    float4 f1 = *(const float4*)(src + off + 4);
    short8 o;
    o[0] = (short)f2bf(f0.x); o[1] = (short)f2bf(f0.y);
    o[2] = (short)f2bf(f0.z); o[3] = (short)f2bf(f0.w);
    o[4] = (short)f2bf(f1.x); o[5] = (short)f2bf(f1.y);
    o[6] = (short)f2bf(f1.z); o[7] = (short)f2bf(f1.w);
    *(short8*)(dst + off) = o;
}

// Tile: 128 batch rows x (32 hidden cols x 4 gates = 128 virtual cols), BK=32.
// Wave w: rows (w>>1)*64, col-half (w&1); its 4 col-tiles are the 4 gates at one
// 16-wide j range -> gate epilogue is register-local per lane/reg.
// Outputs are FLOAT32: h_next [8M] then c_next [8M].
__global__ __launch_bounds__(256) void lstm_cell_kernel(
    const ushort_t* __restrict__ Xb,  const ushort_t* __restrict__ Hb,
    const ushort_t* __restrict__ Wb,  // 8 slots of [H][K] bf16: i,f,g,o (x) then i,f,g,o (h)
    const float* __restrict__ Cprev,
    const float* __restrict__ Bi, const float* __restrict__ Bf,
    const float* __restrict__ Bg, const float* __restrict__ Bo,
    float* __restrict__ Out)
{
    __shared__ __align__(16) ushort_t As[128 * 32];
    __shared__ __align__(16) ushort_t Bs[128 * 32];

    const int t   = threadIdx.x;
    const int bm0 = blockIdx.y * 128;
    const int j0  = blockIdx.x * 32;

    // ---- staging addressing: 512 16B-chunks per tile, 2 per thread ----
    const int idx0 = t, idx1 = t + 256;
    const int rA0 = idx0 >> 2, kA0 = (idx0 & 3) * 8;
    const int rA1 = idx1 >> 2, kA1 = (idx1 & 3) * 8;

    const ushort_t* xA0 = Xb + (size_t)(bm0 + rA0) * IN_ + kA0;
    const ushort_t* xA1 = Xb + (size_t)(bm0 + rA1) * IN_ + kA1;
    const ushort_t* hA0 = Hb + (size_t)(bm0 + rA0) * H_  + kA0;
    const ushort_t* hA1 = Hb + (size_t)(bm0 + rA1) * H_  + kA1;

    // weights: virtual row v -> gate (v>>4)&3, j = j0 + (v>>6)*16 + (v&15)
    const int g0 = (rA0 >> 4) & 3, g1 = (rA1 >> 4) & 3;
    const int jj0_ = j0 + ((rA0 >> 6) << 4) + (rA0 & 15);
    const int jj1_ = j0 + ((rA1 >> 6) << 4) + (rA1 & 15);
    const ushort_t* wx0 = Wb + (size_t)g0 * WB_ELEMS + (size_t)jj0_ * IN_ + kA0;
    const ushort_t* wx1 = Wb + (size_t)g1 * WB_ELEMS + (size_t)jj1_ * IN_ + kA1;
    const ushort_t* wh0 = Wb + (size_t)(4 + g0) * WB_ELEMS + (size_t)jj0_ * H_ + kA0;
    const ushort_t* wh1 = Wb + (size_t)(4 + g1) * WB_ELEMS + (size_t)jj1_ * H_ + kA1;

    ushort_t* ldsA0 = &As[idx0 * 8];
    ushort_t* ldsA1 = &As[idx1 * 8];
    ushort_t* ldsB0 = &Bs[idx0 * 8];
    ushort_t* ldsB1 = &Bs[idx1 * 8];

    // ---- compute-side fragment addressing ----
    const int lane = t & 63;
    const int w = t >> 6;
    const int lr = lane & 15, lk = lane >> 4;
    const int rowbase = (w >> 1) * 64;
    const int colhalf = w & 1;
    const int aoff = (rowbase + lr) * 32 + lk * 8;
    const int boff = (colhalf * 64 + lr) * 32 + lk * 8;

    floatx4 acc[4][4] = {};   // [row-tile][gate]

    for (int phase = 0; phase < 2; ++phase) {
        const ushort_t* a0 = phase ? hA0 : xA0;
        const ushort_t* a1 = phase ? hA1 : xA1;
        const ushort_t* b0 = phase ? wh0 : wx0;
        const ushort_t* b1 = phase ? wh1 : wx1;
        for (int k0 = 0; k0 < 1024; k0 += 32) {
            short8 va0 = *(const short8*)a0;
            short8 va1 = *(const short8*)a1;
            short8 vb0 = *(const short8*)b0;
            short8 vb1 = *(const short8*)b1;
            a0 += 32; a1 += 32; b0 += 32; b1 += 32;

            __syncthreads();
            *(short8*)ldsA0 = va0;
            *(short8*)ldsA1 = va1;
            *(short8*)ldsB0 = vb0;
            *(short8*)ldsB1 = vb1;
            __syncthreads();

            short8 af[4], bfr[4];
            #pragma unroll
            for (int rt = 0; rt < 4; ++rt)
                af[rt] = *(const short8*)(&As[aoff + rt * 512]);
            #pragma unroll
            for (int ct = 0; ct < 4; ++ct)
                bfr[ct] = *(const short8*)(&Bs[boff + ct * 512]);
            #pragma unroll
            for (int rt = 0; rt < 4; ++rt)
                #pragma unroll
                for (int ct = 0; ct < 4; ++ct)
                    acc[rt][ct] = __builtin_amdgcn_mfma_f32_16x16x32_bf16(
                        af[rt], bfr[ct], acc[rt][ct], 0, 0, 0);
        }
    }

    // ---- epilogue: 4 gates live in acc[rt][0..3], same lane/reg ----
    const int j = j0 + colhalf * 16 + lr;
    const float bi = Bi[j], bff = Bf[j], bg = Bg[j], bo = Bo[j];

    #pragma unroll
    for (int rt = 0; rt < 4; ++rt) {
        #pragma unroll
        for (int reg = 0; reg < 4; ++reg) {
            const int m = bm0 + rowbase + rt * 16 + lk * 4 + reg;
            const float zi = acc[rt][0][reg] + bi;
            const float zf = acc[rt][1][reg] + bff;
            const float zg = acc[rt][2][reg] + bg;
            const float zo = acc[rt][3][reg] + bo;
            const float ig = sigmoid_(zi);
            const float fg = sigmoid_(zf);
            const float gg = tanh_(zg);
            const float og = sigmoid_(zo);
            const float cp = Cprev[(size_t)m * H_ + j];
            const float cn = fg * cp + ig * gg;
            const float hn = og * tanh_(cn);
            Out[(size_t)m * H_ + j] = hn;                             // h_next (f32)
            Out[(size_t)B_ * H_ + (size_t)m * H_ + j] = cn;           // c_next (f32)
        }
    }
}

extern "C" void kernel_launch(void* const* d_in, const int* in_sizes, int n_in,
                              void* d_out, int out_size, void* d_ws, size_t ws_size,
                              hipStream_t stream)
{
    (void)in_sizes; (void)n_in; (void)out_size; (void)ws_size;
    const float* X   = (const float*)d_in[0];
    const float* Hin = (const float*)d_in[1];
    const float* Cp  = (const float*)d_in[2];
    const float* Wfx = (const float*)d_in[3];
    const float* Bf  = (const float*)d_in[4];
    const float* Wfh = (const float*)d_in[5];
    const float* Wix = (const float*)d_in[6];
    const float* Bi  = (const float*)d_in[7];
    const float* Wih = (const float*)d_in[8];
    const float* Wgx = (const float*)d_in[9];
    const float* Bg  = (const float*)d_in[10];
    const float* Wgh = (const float*)d_in[11];
    const float* Wox = (const float*)d_in[12];
    const float* Bo  = (const float*)d_in[13];
    const float* Woh = (const float*)d_in[14];
    float* Out = (float*)d_out;
    ushort_t* ws  = (ushort_t*)d_ws;

    // prep: f32 -> bf16 (x, h, 8 weights) into ws
    cvt_kernel<<<dim3(12288), dim3(256), 0, stream>>>(
        X, Hin, Wix, Wfx, Wgx, Wox, Wih, Wfh, Wgh, Woh, ws);

    dim3 grid(H_ / 32, B_ / 128);   // 32 x 64 = 2048 blocks
    lstm_cell_kernel<<<grid, dim3(256), 0, stream>>>(
        ws + WS_XB, ws + WS_HB, ws + WS_WB,
        Cp, Bi, Bf, Bg, Bo, Out);
}

// Round 5
// 344.909 us; speedup vs baseline: 1.0902x; 1.0902x over previous
//
#include <hip/hip_runtime.h>
#include <stdint.h>

typedef unsigned short ushort_t;
typedef __attribute__((ext_vector_type(8))) short short8;
typedef __attribute__((ext_vector_type(4))) float floatx4;

#define B_   8192
#define IN_  1024
#define H_   1024

#define XB_ELEMS   (B_ * IN_)            // 8388608
#define WB_ELEMS   (H_ * IN_)            // 1048576
// ws layout (ushort elements): Xb[8M] | Hb[8M] | Wb[8][1M]  (slots: i,f,g,o x-weights then i,f,g,o h-weights)
#define WS_XB   0
#define WS_HB   XB_ELEMS
#define WS_WB   (2 * XB_ELEMS)

__device__ __forceinline__ ushort_t f2bf(float f) {
    union { float f; uint32_t i; } v; v.f = f;
    uint32_t r = (v.i + 0x7fffu + ((v.i >> 16) & 1u)) >> 16;
    return (ushort_t)r;
}
__device__ __forceinline__ float sigmoid_(float x) {
    return 1.0f / (1.0f + __expf(-x));
}
__device__ __forceinline__ float tanh_(float x) {
    float xc = fminf(fmaxf(x, -20.f), 20.f);
    float e = __expf(2.f * xc);
    return (e - 1.f) / (e + 1.f);
}

// async global->LDS DMA, 16B per lane. LDS dest must be wave-uniform base +
// lane*16 (our idx-contiguous layout guarantees this). Proper addrspacecast,
// NOT integer truncation of the flat pointer.
__device__ __forceinline__ void gll16(const ushort_t* gsrc, ushort_t* ldst) {
    __builtin_amdgcn_global_load_lds(
        (const __attribute__((address_space(1))) void*)gsrc,
        (__attribute__((address_space(3))) void*)ldst,
        16, 0, 0);
}

// ---- prep: f32 -> bf16 for x, h, 8 weight matrices into ws ----
__global__ __launch_bounds__(256) void cvt_kernel(
    const float* __restrict__ X,   const float* __restrict__ Hin,
    const float* __restrict__ Wix, const float* __restrict__ Wfx,
    const float* __restrict__ Wgx, const float* __restrict__ Wox,
    const float* __restrict__ Wih, const float* __restrict__ Wfh,
    const float* __restrict__ Wgh, const float* __restrict__ Woh,
    ushort_t* __restrict__ ws)
{
    const int c = blockIdx.x * 256 + threadIdx.x;
    const float* src;
    ushort_t* dst;
    int off;
    if (c < 2097152) {
        const int t = c >> 20;                 // 0 = x, 1 = h
        src = t ? Hin : X;
        dst = ws + (t ? WS_HB : WS_XB);
        off = (c & 1048575) * 8;
    } else {
        const int cc = c - 2097152;
        const int s = cc >> 17;                // weight slot 0..7
        const float* w =
            s == 0 ? Wix : s == 1 ? Wfx : s == 2 ? Wgx : s == 3 ? Wox :
            s == 4 ? Wih : s == 5 ? Wfh : s == 6 ? Wgh : Woh;
        src = w;
        dst = ws + WS_WB + s * WB_ELEMS;
        off = (cc & 131071) * 8;
    }
    float4 f0 = *(const float4*)(src + off);
    float4 f1 = *(const float4*)(src + off + 4);
    short8 o;
    o[0] = (short)f2bf(f0.x); o[1] = (short)f2bf(f0.y);
    o[2] = (short)f2bf(f0.z); o[3] = (short)f2bf(f0.w);
    o[4] = (short)f2bf(f1.x); o[5] = (short)f2bf(f1.y);
    o[6] = (short)f2bf(f1.z); o[7] = (short)f2bf(f1.w);
    *(short8*)(dst + off) = o;
}

// Tile: 128 batch rows x (32 hidden cols x 4 gates = 128 virtual cols), BK=32.
// Wave w: rows (w>>1)*64, col-half (w&1); its 4 col-tiles are the 4 gates at one
// 16-wide j range -> gate epilogue is register-local per lane/reg.
// Staging: global_load_lds width-16 (m97 structure). Outputs FLOAT32: h then c.
__global__ __launch_bounds__(256) void lstm_cell_kernel(
    const ushort_t* __restrict__ Xb,  const ushort_t* __restrict__ Hb,
    const ushort_t* __restrict__ Wb,  // 8 slots of [H][K] bf16: i,f,g,o (x) then i,f,g,o (h)
    const float* __restrict__ Cprev,
    const float* __restrict__ Bi, const float* __restrict__ Bf,
    const float* __restrict__ Bg, const float* __restrict__ Bo,
    float* __restrict__ Out)
{
    __shared__ __align__(16) ushort_t As[128 * 32];
    __shared__ __align__(16) ushort_t Bs[128 * 32];

    const int t   = threadIdx.x;
    const int bm0 = blockIdx.y * 128;
    const int j0  = blockIdx.x * 32;

    // ---- staging addressing: 512 16B-chunks per tile, 2 per thread ----
    const int idx0 = t, idx1 = t + 256;
    const int rA0 = idx0 >> 2, kA0 = (idx0 & 3) * 8;
    const int rA1 = idx1 >> 2, kA1 = (idx1 & 3) * 8;

    const ushort_t* xA0 = Xb + (size_t)(bm0 + rA0) * IN_ + kA0;
    const ushort_t* xA1 = Xb + (size_t)(bm0 + rA1) * IN_ + kA1;
    const ushort_t* hA0 = Hb + (size_t)(bm0 + rA0) * H_  + kA0;
    const ushort_t* hA1 = Hb + (size_t)(bm0 + rA1) * H_  + kA1;

    // weights: virtual row v -> gate (v>>4)&3, j = j0 + (v>>6)*16 + (v&15)
    const int g0 = (rA0 >> 4) & 3, g1 = (rA1 >> 4) & 3;
    const int jj0_ = j0 + ((rA0 >> 6) << 4) + (rA0 & 15);
    const int jj1_ = j0 + ((rA1 >> 6) << 4) + (rA1 & 15);
    const ushort_t* wx0 = Wb + (size_t)g0 * WB_ELEMS + (size_t)jj0_ * IN_ + kA0;
    const ushort_t* wx1 = Wb + (size_t)g1 * WB_ELEMS + (size_t)jj1_ * IN_ + kA1;
    const ushort_t* wh0 = Wb + (size_t)(4 + g0) * WB_ELEMS + (size_t)jj0_ * H_ + kA0;
    const ushort_t* wh1 = Wb + (size_t)(4 + g1) * WB_ELEMS + (size_t)jj1_ * H_ + kA1;

    ushort_t* ldsA0 = &As[idx0 * 8];
    ushort_t* ldsA1 = &As[idx1 * 8];
    ushort_t* ldsB0 = &Bs[idx0 * 8];
    ushort_t* ldsB1 = &Bs[idx1 * 8];

    // ---- compute-side fragment addressing ----
    const int lane = t & 63;
    const int w = t >> 6;
    const int lr = lane & 15, lk = lane >> 4;
    const int rowbase = (w >> 1) * 64;
    const int colhalf = w & 1;
    const int aoff = (rowbase + lr) * 32 + lk * 8;
    const int boff = (colhalf * 64 + lr) * 32 + lk * 8;

    floatx4 acc[4][4] = {};   // [row-tile][gate]

    for (int phase = 0; phase < 2; ++phase) {
        const ushort_t* a0 = phase ? hA0 : xA0;
        const ushort_t* a1 = phase ? hA1 : xA1;
        const ushort_t* b0 = phase ? wh0 : wx0;
        const ushort_t* b1 = phase ? wh1 : wx1;
        for (int k0 = 0; k0 < 1024; k0 += 32) {
            gll16(a0, ldsA0);
            gll16(a1, ldsA1);
            gll16(b0, ldsB0);
            gll16(b1, ldsB1);
            a0 += 32; a1 += 32; b0 += 32; b1 += 32;
            __syncthreads();   // compiler drains vmcnt before s_barrier -> DMA done

            short8 af[4], bfr[4];
            #pragma unroll
            for (int rt = 0; rt < 4; ++rt)
                af[rt] = *(const short8*)(&As[aoff + rt * 512]);
            #pragma unroll
            for (int ct = 0; ct < 4; ++ct)
                bfr[ct] = *(const short8*)(&Bs[boff + ct * 512]);
            #pragma unroll
            for (int rt = 0; rt < 4; ++rt)
                #pragma unroll
                for (int ct = 0; ct < 4; ++ct)
                    acc[rt][ct] = __builtin_amdgcn_mfma_f32_16x16x32_bf16(
                        af[rt], bfr[ct], acc[rt][ct], 0, 0, 0);
            __syncthreads();   // fragment reads done before next iter's DMA overwrite
        }
    }

    // ---- epilogue: 4 gates live in acc[rt][0..3], same lane/reg ----
    const int j = j0 + colhalf * 16 + lr;
    const float bi = Bi[j], bff = Bf[j], bg = Bg[j], bo = Bo[j];

    #pragma unroll
    for (int rt = 0; rt < 4; ++rt) {
        #pragma unroll
        for (int reg = 0; reg < 4; ++reg) {
            const int m = bm0 + rowbase + rt * 16 + lk * 4 + reg;
            const float zi = acc[rt][0][reg] + bi;
            const float zf = acc[rt][1][reg] + bff;
            const float zg = acc[rt][2][reg] + bg;
            const float zo = acc[rt][3][reg] + bo;
            const float ig = sigmoid_(zi);
            const float fg = sigmoid_(zf);
            const float gg = tanh_(zg);
            const float og = sigmoid_(zo);
            const float cp = Cprev[(size_t)m * H_ + j];
            const float cn = fg * cp + ig * gg;
            const float hn = og * tanh_(cn);
            Out[(size_t)m * H_ + j] = hn;                             // h_next (f32)
            Out[(size_t)B_ * H_ + (size_t)m * H_ + j] = cn;           // c_next (f32)
        }
    }
}

extern "C" void kernel_launch(void* const* d_in, const int* in_sizes, int n_in,
                              void* d_out, int out_size, void* d_ws, size_t ws_size,
                              hipStream_t stream)
{
    (void)in_sizes; (void)n_in; (void)out_size; (void)ws_size;
    const float* X   = (const float*)d_in[0];
    const float* Hin = (const float*)d_in[1];
    const float* Cp  = (const float*)d_in[2];
    const float* Wfx = (const float*)d_in[3];
    const float* Bf  = (const float*)d_in[4];
    const float* Wfh = (const float*)d_in[5];
    const float* Wix = (const float*)d_in[6];
    const float* Bi  = (const float*)d_in[7];
    const float* Wih = (const float*)d_in[8];
    const float* Wgx = (const float*)d_in[9];
    const float* Bg  = (const float*)d_in[10];
    const float* Wgh = (const float*)d_in[11];
    const float* Wox = (const float*)d_in[12];
    const float* Bo  = (const float*)d_in[13];
    const float* Woh = (const float*)d_in[14];
    float* Out = (float*)d_out;
    ushort_t* ws  = (ushort_t*)d_ws;

    // prep: f32 -> bf16 (x, h, 8 weights) into ws
    cvt_kernel<<<dim3(12288), dim3(256), 0, stream>>>(
        X, Hin, Wix, Wfx, Wgx, Wox, Wih, Wfh, Wgh, Woh, ws);

    dim3 grid(H_ / 32, B_ / 128);   // 32 x 64 = 2048 blocks
    lstm_cell_kernel<<<grid, dim3(256), 0, stream>>>(
        ws + WS_XB, ws + WS_HB, ws + WS_WB,
        Cp, Bi, Bf, Bg, Bo, Out);
}